// Round 6
// baseline (186.496 us; speedup 1.0000x reference)
//
#include <hip/hip_runtime.h>
#include <hip/hip_bf16.h>

// Rounds 0-16 established: fp32 inputs (inline detector), fp32 out, all
// heavy math in bf16 MFMA. R10: reg prefetch before __syncthreads is
// DEFEATED (barrier drains vmcnt). R12: swapped-QK attn (S^T=mfma(K,Q)),
// lane-local softmax, exp2-domain, rescale-skip. R13: zero-LDS P path via
// sigma slot permutation; proved attn is STALL-bound not LDS-bound.
// R14: 512-thr attn + complementary pairing. R15/R16: gload_lds GEMM
// staging + TLP restore + dispatch fusion: all ~flat -> the remaining attn
// cost is its barrier-synced staging structure itself.
// R17 (this round): BARRIER-FREE attn (m169: don't stage what L2-fits).
//  - gemm1's v-epilogue writes V directly in MFMA B-frag order
//    (vfrag[bh][tile][kc][c2][lane][j], sigma folded into the WRITE
//    address; same uint2 stores, better coalesced than old stride-T v_t).
//  - attn loads K/V/Q fragments straight from global (each a fully
//    coalesced 1KB b128 per wave, L2-resident): ZERO LDS, ZERO barriers,
//    4096 independent wave-tasks (bh x 128 q-tiles of 16 rows),
//    heavy-first order. Waves self-schedule; no stall amplification.
//  - prep: converts + fold fused (5 -> 4 dispatches).
// Pre-committed: if total flat +-3 again, harness floor reached -> present
// roofline arithmetic next round.
#define B_  2
#define T_  2048
#define D_  1024
#define H_  16
#define DH_ 64
#define R_  32
#define BT_ (B_*T_)          // 4096
#define BH_ (B_*H_)          // 32

typedef unsigned short u16;
typedef unsigned int   u32;
typedef __attribute__((ext_vector_type(8))) short bhalf8;   // 8 bf16 = 4 VGPRs
typedef __attribute__((ext_vector_type(4))) float floatx4;  // MFMA C/D

// Workspace layout (bytes). Total ~38 MB.
#define WSB_FLAG  0
#define WSB_XB    256                        // bf16 x     (4096,1024)  8 MB
#define WSB_WCATT (WSB_XB    + 8388608)      // bf16 WcatT (2048,1024)  4 MB
#define WSB_QL    (WSB_WCATT + 4194304)      // bf16 (B,H,T,R)          4 MB
#define WSB_KL    (WSB_QL    + 4194304)      // bf16 (B,H,T,R)          4 MB
#define WSB_VT    (WSB_KL    + 4194304)      // bf16 vfrag (B,H,...)    8 MB
#define WSB_YB    (WSB_VT    + 8388608)      // bf16 y     (B,T,D)      8 MB
#define WSB_WOT   (WSB_YB    + 8388608)      // bf16 WoT   (1024,1024)  2 MB

#define NEG_ -1.0e30f

__device__ __forceinline__ float bfs(u16 s) {
    union { u32 i; float f; } w; w.i = ((u32)s) << 16; return w.f;
}
__device__ __forceinline__ u16 tob(float f) {
    __hip_bfloat16 h = __float2bfloat16(f);   // RNE
    return *(u16*)&h;
}
__device__ __forceinline__ u32 pack2(float a, float b) {
    return (u32)tob(a) | ((u32)tob(b) << 16);
}
// Direct global->LDS staging, 16B/lane. LDS base wave-uniform; HW writes
// base + lane*16. Global address is per-lane.
__device__ __forceinline__ void gload16(const u16* g, u16* l) {
    __builtin_amdgcn_global_load_lds(
        (const __attribute__((address_space(1))) void*)g,
        (__attribute__((address_space(3))) void*)l, 16, 0, 0);
}
// Inline dtype detect (1 = bf16, 0 = fp32) from first 2KB of x.
__device__ __forceinline__ int detect_isbf(const u32* __restrict__ xw, int lane) {
    int hits = 0;
    #pragma unroll
    for (int i = 0; i < 8; ++i) {
        const u32 w = xw[lane + i * 64];
        const u32 h = w & 0xFFFFu;
        const u32 e = (h >> 7) & 0xFFu;
        if (h == 0u || (e >= 100u && e <= 150u)) ++hits;
    }
    #pragma unroll
    for (int off = 32; off; off >>= 1) hits += __shfl_down(hits, off, 64);
    return __shfl(hits, 0, 64) >= 300;
}

// ---------------------------------------------------------------------------
// Kernel P (R17): fused preprocessing.
//  blocks 0..2047   : x -> xb bf16 (8 elems/thread)
//  blocks 2048..2303: transposing convert W_v slice of Wqkv -> WcatT[1024..]
//  blocks 2304..2559: transposing convert W_o -> WoT
//  blocks 2560..2687: fold via MFMA (Wq_lsr/Wk_lsr/core folded into WcatT;
//                     scale includes 1/sqrt(32)*log2(e) for exp2 softmax)
// ---------------------------------------------------------------------------
__global__ __launch_bounds__(256) void prep_kernel(
    const void* __restrict__ x, u16* __restrict__ xb,
    const void* __restrict__ Wqkv, const void* __restrict__ Wo,
    const void* __restrict__ Wq_lsr, const void* __restrict__ Wk_lsr,
    const void* __restrict__ core,
    u16* __restrict__ WcatT, u16* __restrict__ WoT)
{
    __shared__ __align__(16) u16 Bq[128 * 72];   // fold [n=d][k=dh]; also T-tile
    __shared__ __align__(16) u16 Bk[128 * 72];
    __shared__ __align__(16) u16 Aq[32 * 72];    // fold [m=r][k=dh]
    __shared__ __align__(16) u16 Ak[32 * 72];
    const int tid  = threadIdx.x;
    const int lane = tid & 63;
    const int isbf = detect_isbf((const u32*)x, lane);
    const int blk  = blockIdx.x;
    const int w    = tid >> 6;
    const int n16  = lane & 15;
    const int q4   = lane >> 4;

    if (blk < 2048) {
        const int e = blk * 256 + tid;           // over 524288 (x8 elems)
        if (isbf) {
            ((uint4*)xb)[e] = ((const uint4*)x)[e];
        } else {
            float4 a0 = ((const float4*)x)[2*e];
            float4 a1 = ((const float4*)x)[2*e + 1];
            uint4 o;
            o.x = pack2(a0.x, a0.y); o.y = pack2(a0.z, a0.w);
            o.z = pack2(a1.x, a1.y); o.w = pack2(a1.z, a1.w);
            ((uint4*)xb)[e] = o;
        }
        return;
    }

    if (blk < 2560) {
        // transposing convert, 64x64 tiles (uses Bq as scratch tile)
        int t = blk - 2048;
        const void* src; u16* dst; int srcStride, srcColOff, dstRowOff;
        if (t < 256) { src = Wqkv; dst = WcatT; srcStride = 3*D_; srcColOff = 2*D_; dstRowOff = 1024; }
        else { t -= 256; src = Wo; dst = WoT; srcStride = D_; srcColOff = 0; dstRowOff = 0; }
        const int j0 = (t & 15) * 64;
        const int i0 = (t >> 4) * 64;
        #pragma unroll
        for (int p = 0; p < 2; ++p) {
            const int e = tid + p * 256;
            const int r = e >> 3, ch = e & 7;
            if (isbf) {
                uint4 v = *(const uint4*)((const u16*)src + (size_t)(i0 + r) * srcStride + srcColOff + j0 + ch*8);
                *(uint4*)&Bq[r * 72 + ch*8] = v;
            } else {
                const float* s = (const float*)src + (size_t)(i0 + r) * srcStride + srcColOff + j0 + ch*8;
                float4 a0 = *(const float4*)s;
                float4 a1 = *(const float4*)(s + 4);
                uint4 o;
                o.x = pack2(a0.x, a0.y); o.y = pack2(a0.z, a0.w);
                o.z = pack2(a1.x, a1.y); o.w = pack2(a1.z, a1.w);
                *(uint4*)&Bq[r * 72 + ch*8] = o;
            }
        }
        __syncthreads();
        #pragma unroll
        for (int p = 0; p < 2; ++p) {
            const int e = tid + p * 256;
            const int c = e >> 3, ch = e & 7;
            u16 tmp[8];
            #pragma unroll
            for (int j = 0; j < 8; ++j) tmp[j] = Bq[(ch*8 + j) * 72 + c];
            *(uint4*)(dst + (size_t)(dstRowOff + j0 + c) * D_ + i0 + ch*8) = *(uint4*)tmp;
        }
        return;
    }

    // fold: per head h, Cq(32x1024) = Aq_h^T(32x64) @ Wq_h(64x1024)
    const int fb = blk - 2560;          // 0..127
    const int h  = fb & 15;
    const int d0 = (fb >> 4) * 128;

    #pragma unroll
    for (int p = 0; p < 8; ++p) {
        const int e  = tid + p * 256;
        const int r  = e & 31, dh = e >> 5;
        float aq, ak;
        if (isbf) {
            aq = bfs(((const u16*)Wq_lsr)[(h*DH_ + dh)*R_ + r]);
            ak = bfs(((const u16*)Wk_lsr)[(h*DH_ + dh)*R_ + r]);
        } else {
            aq = ((const float*)Wq_lsr)[(h*DH_ + dh)*R_ + r];
            ak = ((const float*)Wk_lsr)[(h*DH_ + dh)*R_ + r];
        }
        Aq[r * 72 + dh] = tob(aq);
        Ak[r * 72 + dh] = tob(ak);
    }
    #pragma unroll
    for (int p = 0; p < 8; ++p) {
        const int e  = tid + p * 256;      // 0..2047
        const int n  = e >> 4, ch = e & 15;
        if (isbf) {
            uint2 wq = *(const uint2*)((const u16*)Wqkv + (size_t)(d0+n)*(3*D_) + h*DH_ + ch*4);
            uint2 wk = *(const uint2*)((const u16*)Wqkv + (size_t)(d0+n)*(3*D_) + D_ + h*DH_ + ch*4);
            *(uint2*)&Bq[n * 72 + ch*4] = wq;
            *(uint2*)&Bk[n * 72 + ch*4] = wk;
        } else {
            float4 fq = *(const float4*)((const float*)Wqkv + (size_t)(d0+n)*(3*D_) + h*DH_ + ch*4);
            float4 fk = *(const float4*)((const float*)Wqkv + (size_t)(d0+n)*(3*D_) + D_ + h*DH_ + ch*4);
            uint2 oq, ok;
            oq.x = pack2(fq.x, fq.y); oq.y = pack2(fq.z, fq.w);
            ok.x = pack2(fk.x, fk.y); ok.y = pack2(fk.z, fk.w);
            *(uint2*)&Bq[n * 72 + ch*4] = oq;
            *(uint2*)&Bk[n * 72 + ch*4] = ok;
        }
    }
    __syncthreads();

    floatx4 accq[2][2], acck[2][2];
    #pragma unroll
    for (int mi = 0; mi < 2; ++mi)
        #pragma unroll
        for (int ni = 0; ni < 2; ++ni) { accq[mi][ni] = (floatx4)(0.f); acck[mi][ni] = (floatx4)(0.f); }

    #pragma unroll
    for (int kk = 0; kk < 2; ++kk) {
        bhalf8 aqf[2], akf[2], bqf[2], bkf[2];
        #pragma unroll
        for (int mi = 0; mi < 2; ++mi) {
            aqf[mi] = *(const bhalf8*)&Aq[(mi*16 + n16) * 72 + kk*32 + q4*8];
            akf[mi] = *(const bhalf8*)&Ak[(mi*16 + n16) * 72 + kk*32 + q4*8];
        }
        #pragma unroll
        for (int ni = 0; ni < 2; ++ni) {
            bqf[ni] = *(const bhalf8*)&Bq[(w*32 + ni*16 + n16) * 72 + kk*32 + q4*8];
            bkf[ni] = *(const bhalf8*)&Bk[(w*32 + ni*16 + n16) * 72 + kk*32 + q4*8];
        }
        #pragma unroll
        for (int mi = 0; mi < 2; ++mi)
            #pragma unroll
            for (int ni = 0; ni < 2; ++ni) {
                accq[mi][ni] = __builtin_amdgcn_mfma_f32_16x16x32_bf16(aqf[mi], bqf[ni], accq[mi][ni], 0, 0, 0);
                acck[mi][ni] = __builtin_amdgcn_mfma_f32_16x16x32_bf16(akf[mi], bkf[ni], acck[mi][ni], 0, 0, 0);
            }
    }

    const float scale = (float)(0.17677669529663687 * 1.4426950408889634);
    #pragma unroll
    for (int mi = 0; mi < 2; ++mi) {
        #pragma unroll
        for (int rr = 0; rr < 4; ++rr) {
            const int r = mi*16 + q4*4 + rr;
            const float cc = (isbf ? bfs(((const u16*)core)[h*R_ + r])
                                   : ((const float*)core)[h*R_ + r]) * scale;
            #pragma unroll
            for (int ni = 0; ni < 2; ++ni) {
                const int d = d0 + w*32 + ni*16 + n16;
                WcatT[(size_t)(h*R_ + r) * D_ + d]       = tob(accq[mi][ni][rr] * cc);
                WcatT[(size_t)(512 + h*R_ + r) * D_ + d] = tob(acck[mi][ni][rr]);
            }
        }
    }
}

// ---------------------------------------------------------------------------
// Kernel 1 (R17): MFMA gemm1  xb(4096,1024) @ WcatT^T -> ql/kl + vfrag.
// 128x64 tile, BK=64, gload16 staging, 1024 blocks = 4/CU (R16).
// v-epilogue now writes vfrag: V in attn's MFMA B-fragment order,
// vfrag[bh][tile][kc][c2][lane=(q4v*16+dh&15)][j], sigma folded in:
// s = 32*kc + 16*j2 + 4*q4v + j10 (j = j2*4 + j10, j10 = rr).
// ---------------------------------------------------------------------------
__global__ __launch_bounds__(256, 4) void gemm1_mfma(
    const u16* __restrict__ xb, const u16* __restrict__ WcatT,
    u16* __restrict__ ql, u16* __restrict__ kl, u16* __restrict__ vf)
{
    __shared__ __align__(16) u16 As[128 * 64];   // 16384 B, linear
    __shared__ __align__(16) u16 Bs[64 * 64];    //  8192 B, linear
    const int tid  = threadIdx.x;
    const int lane = tid & 63;
    const int w    = tid >> 6;
    const int n16  = lane & 15;
    const int q4   = lane >> 4;
    const int wx   = w & 1;          // n-half (32 cols)
    const int wy   = w >> 1;         // m-half (64 rows)
    const int bm   = blockIdx.y * 128;
    const int bn   = blockIdx.x * 64;
    const int lrow = lane >> 3;          // 0..7: row within 8-row stripe
    const int lcol = (lane & 7) * 8;     // u16 col within 64-col row

    floatx4 acc[4][2];
    #pragma unroll
    for (int i = 0; i < 4; ++i)
        #pragma unroll
        for (int j = 0; j < 2; ++j) acc[i][j] = (floatx4)(0.f);

    for (int kt = 0; kt < D_; kt += 64) {
        #pragma unroll
        for (int i = 0; i < 4; ++i) {
            const int r0 = w*32 + i*8;
            gload16(xb + (size_t)(bm + r0 + lrow) * D_ + kt + lcol, &As[r0 * 64]);
        }
        #pragma unroll
        for (int i = 0; i < 2; ++i) {
            const int r0 = w*16 + i*8;
            gload16(WcatT + (size_t)(bn + r0 + lrow) * D_ + kt + lcol, &Bs[r0 * 64]);
        }
        __syncthreads();
        #pragma unroll
        for (int kk = 0; kk < 2; ++kk) {
            bhalf8 a[4], b[2];
            #pragma unroll
            for (int mi = 0; mi < 4; ++mi)
                a[mi] = *(const bhalf8*)&As[(wy*64 + mi*16 + n16) * 64 + kk*32 + q4*8];
            #pragma unroll
            for (int ni = 0; ni < 2; ++ni)
                b[ni] = *(const bhalf8*)&Bs[(wx*32 + ni*16 + n16) * 64 + kk*32 + q4*8];
            #pragma unroll
            for (int mi = 0; mi < 4; ++mi)
                #pragma unroll
                for (int ni = 0; ni < 2; ++ni)
                    acc[mi][ni] = __builtin_amdgcn_mfma_f32_16x16x32_bf16(
                        a[mi], b[ni], acc[mi][ni], 0, 0, 0);
        }
        __syncthreads();
    }

    if (bn < 1024) {
        #pragma unroll
        for (int mi = 0; mi < 4; ++mi) {
            #pragma unroll
            for (int rr = 0; rr < 4; ++rr) {
                const int row = bm + wy*64 + mi*16 + q4*4 + rr;
                const int b   = row >> 11;
                const int t   = row & (T_ - 1);
                #pragma unroll
                for (int ni = 0; ni < 2; ++ni) {
                    const int col = bn + wx*32 + ni*16 + n16;
                    const u16 val = tob(acc[mi][ni][rr]);
                    if (col < 512) {
                        const int h = col >> 5, r = col & 31;
                        ql[((size_t)(b*H_ + h)*T_ + t)*R_ + r] = val;
                    } else {
                        const int c = col - 512; const int h = c >> 5, r = c & 31;
                        kl[((size_t)(b*H_ + h)*T_ + t)*R_ + r] = val;
                    }
                }
            }
        }
    } else {
        // v -> vfrag (attn B-frag order). Thread owns V[t..t+3][dh].
        #pragma unroll
        for (int mi = 0; mi < 4; ++mi) {
            const int row0 = bm + wy*64 + mi*16 + q4*4;   // multiple of 4
            const int b  = row0 >> 11;
            const int t  = row0 & (T_ - 1);
            const int tile = t >> 7;
            const int sl   = t & 127;                     // sl % 4 == 0
            const int kc   = sl >> 5;
            const int j2   = (sl >> 4) & 1;
            const int qv   = (sl >> 2) & 3;
            #pragma unroll
            for (int ni = 0; ni < 2; ++ni) {
                const int c  = bn - 1024 + wx*32 + ni*16 + n16;  // 0..1023
                const int h  = c >> 6, dh = c & 63;
                const int bh = b*H_ + h;
                const int c2 = dh >> 4;
                const int lv = qv*16 + (dh & 15);
                u16* dst = vf + ((((size_t)bh*16 + tile)*4 + kc)*4 + c2)*512
                              + lv*8 + j2*4;
                uint2 o;
                o.x = pack2(acc[mi][ni][0], acc[mi][ni][1]);
                o.y = pack2(acc[mi][ni][2], acc[mi][ni][3]);
                *(uint2*)dst = o;
            }
        }
    }
}

// ---------------------------------------------------------------------------
// softmax update for one 16-row q-group (R13-verified logic).
// ---------------------------------------------------------------------------
__device__ __forceinline__ void softmax_update(
    floatx4 (&Sc)[8], float &mrow, float &lrow, floatx4 (&O)[4], int q4)
{
    float cmax[8];
    #pragma unroll
    for (int c = 0; c < 8; ++c)
        cmax[c] = fmaxf(fmaxf(Sc[c][0], Sc[c][1]), fmaxf(Sc[c][2], Sc[c][3]));
    float rmax = fmaxf(fmaxf(fmaxf(cmax[0], cmax[1]), fmaxf(cmax[2], cmax[3])),
                       fmaxf(fmaxf(cmax[4], cmax[5]), fmaxf(cmax[6], cmax[7])));
    rmax = fmaxf(rmax, __shfl_xor(rmax, 16, 64));
    rmax = fmaxf(rmax, __shfl_xor(rmax, 32, 64));

    const float mn = fmaxf(mrow, rmax);
    const int norescale = __all(rmax <= mrow);     // exact: alpha == 1

    float csum[8];
    #pragma unroll
    for (int c = 0; c < 8; ++c) {
        #pragma unroll
        for (int r = 0; r < 4; ++r)
            Sc[c][r] = __builtin_amdgcn_exp2f(Sc[c][r] - mn);
        csum[c] = (Sc[c][0] + Sc[c][1]) + (Sc[c][2] + Sc[c][3]);
    }
    float rsum = ((csum[0] + csum[1]) + (csum[2] + csum[3]))
               + ((csum[4] + csum[5]) + (csum[6] + csum[7]));
    rsum += __shfl_xor(rsum, 16, 64);
    rsum += __shfl_xor(rsum, 32, 64);

    if (norescale) {
        lrow += rsum;                              // mn == mrow exactly
    } else {
        const float alpha = __builtin_amdgcn_exp2f(mrow - mn);
        mrow = mn;
        lrow = lrow * alpha + rsum;
        float aO[4];
        #pragma unroll
        for (int r = 0; r < 4; ++r) aO[r] = __shfl(alpha, q4*4 + r, 64);
        #pragma unroll
        for (int c2 = 0; c2 < 4; ++c2)
            #pragma unroll
            for (int r = 0; r < 4; ++r) O[c2][r] *= aO[r];
    }
}

// ---------------------------------------------------------------------------
// Kernel 2 (R17): BARRIER-FREE swapped-QK flash attention.
// 4096 independent wave-tasks: task -> (qt = 127 - task>>5, bh = task&31);
// wave owns 16 q-rows (q = 16*qt + n16). All operands load straight from
// global (L2-resident) as coalesced 1KB b128 fragments:
//   Q: ql[(16qt+n16)*32 + q4*8]         (frag layout native)
//   K: kl[(128it+16c+n16)*32 + q4*8]    (frag layout native)
//   V: vfrag[bh][it][kc][c2][lane][j]   (sigma pre-applied by gemm1)
// P packs in-register (R13). No LDS, no __syncthreads, no stall coupling.
// ---------------------------------------------------------------------------
__global__ __launch_bounds__(256, 3) void attn_kernel(
    const u16* __restrict__ ql, const u16* __restrict__ kl,
    const u16* __restrict__ vf, u16* __restrict__ y)
{
    const int tid  = threadIdx.x;
    const int lane = tid & 63;
    const int w    = tid >> 6;
    const int n16  = lane & 15;
    const int q4   = lane >> 4;
    const int task = blockIdx.x * 4 + w;
    const int qt   = 127 - (task >> 5);      // heavy q-tiles first
    const int bh   = task & 31;
    const int nt   = (qt >> 3) + 1;          // # of 128-wide s-tiles

    const u16* qlb = ql + (size_t)bh * T_ * R_;
    const u16* klb = kl + (size_t)bh * T_ * R_;
    const u16* vfb = vf + (size_t)bh * 131072;   // 16 tiles * 8192 u16

    const bhalf8 aq = *(const bhalf8*)(qlb + (size_t)(16*qt + n16) * R_ + q4*8);

    float mrow = NEG_, lrow = 0.f;           // lane owns q-row 16qt + n16
    floatx4 O[4];
    #pragma unroll
    for (int c = 0; c < 4; ++c) O[c] = (floatx4)(0.f);

    for (int it = 0; it < nt; ++it) {
        const u16* kt = klb + (size_t)(it*128 + n16) * R_ + q4*8;
        floatx4 Sc[8];
        #pragma unroll
        for (int c = 0; c < 8; ++c) {
            bhalf8 ak = *(const bhalf8*)(kt + (size_t)(16*c) * R_);
            Sc[c] = __builtin_amdgcn_mfma_f32_16x16x32_bf16(ak, aq, (floatx4)(0.f), 0, 0, 0);
        }

        if (it == nt - 1) {
            const int tq = 16*(qt & 7) + n16;          // local q row in tile
            #pragma unroll
            for (int c = 0; c < 8; ++c) {
                const int sb = 16*c + 4*q4;            // local s base
                #pragma unroll
                for (int r = 0; r < 4; ++r)
                    if (sb + r > tq) Sc[c][r] = NEG_;
            }
        }

        softmax_update(Sc, mrow, lrow, O, q4);

        // PV: A-frag packs from lane's own Sc (R13 sigma order); B-frag is
        // one coalesced b128 per (kc,c2) from vfrag.
        const u16* vt = vfb + (size_t)it * 8192 + lane*8;
        #pragma unroll
        for (int kc = 0; kc < 4; ++kc) {
            union { u32 wd[4]; bhalf8 v; } pu;
            pu.wd[0] = pack2(Sc[2*kc    ][0], Sc[2*kc    ][1]);
            pu.wd[1] = pack2(Sc[2*kc    ][2], Sc[2*kc    ][3]);
            pu.wd[2] = pack2(Sc[2*kc + 1][0], Sc[2*kc + 1][1]);
            pu.wd[3] = pack2(Sc[2*kc + 1][2], Sc[2*kc + 1][3]);
            const bhalf8 pa = pu.v;
            #pragma unroll
            for (int c2 = 0; c2 < 4; ++c2) {
                bhalf8 bv = *(const bhalf8*)(vt + (size_t)(kc*4 + c2) * 512);
                O[c2] = __builtin_amdgcn_mfma_f32_16x16x32_bf16(pa, bv, O[c2], 0, 0, 0);
            }
        }
    }

    // Epilogue: l lives at lane q (= n16, lanes 0..15 authoritative).
    const int b = bh >> 4, h = bh & 15;
    float lb[4];
    #pragma unroll
    for (int r = 0; r < 4; ++r) lb[r] = __shfl(lrow, q4*4 + r, 64);
    #pragma unroll
    for (int r = 0; r < 4; ++r) {
        const float rl = 1.0f / lb[r];
        const int t = 16*qt + q4*4 + r;
        #pragma unroll
        for (int c2 = 0; c2 < 4; ++c2)
            y[((size_t)b * T_ + t) * D_ + h * DH_ + 16*c2 + n16] = tob(O[c2][r] * rl);
    }
}

// ---------------------------------------------------------------------------
// Kernel 3 (R16): MFMA out-gemm  yb(4096,1024) @ WoT^T -> out fp32.
// 64x64 tile, gload16 staging. Grid (16,64) = 1024 blocks = 4/CU.
// ---------------------------------------------------------------------------
__global__ __launch_bounds__(256, 4) void out_gemm_mfma(
    const u16* __restrict__ yb, const u16* __restrict__ WoT,
    float* __restrict__ out)
{
    __shared__ __align__(16) u16 As[64 * 64];   // 8192 B, linear
    __shared__ __align__(16) u16 Bs[64 * 64];   // 8192 B, linear
    const int tid  = threadIdx.x;
    const int lane = tid & 63;
    const int w    = tid >> 6;
    const int n16  = lane & 15;
    const int q4   = lane >> 4;
    const int wx   = w & 1;          // n-half (32 cols)
    const int wy   = w >> 1;         // m-half (32 rows)
    const int bm   = blockIdx.y * 64;
    const int bn   = blockIdx.x * 64;
    const int lrow = lane >> 3;
    const int lcol = (lane & 7) * 8;

    floatx4 acc[2][2];
    #pragma unroll
    for (int i = 0; i < 2; ++i)
        #pragma unroll
        for (int j = 0; j < 2; ++j) acc[i][j] = (floatx4)(0.f);

    for (int kt = 0; kt < D_; kt += 64) {
        #pragma unroll
        for (int i = 0; i < 2; ++i) {
            const int r0 = w*16 + i*8;
            gload16(yb  + (size_t)(bm + r0 + lrow) * D_ + kt + lcol, &As[r0 * 64]);
            gload16(WoT + (size_t)(bn + r0 + lrow) * D_ + kt + lcol, &Bs[r0 * 64]);
        }
        __syncthreads();
        #pragma unroll
        for (int kk = 0; kk < 2; ++kk) {
            bhalf8 a[2], b[2];
            #pragma unroll
            for (int mi = 0; mi < 2; ++mi)
                a[mi] = *(const bhalf8*)&As[(wy*32 + mi*16 + n16) * 64 + kk*32 + q4*8];
            #pragma unroll
            for (int ni = 0; ni < 2; ++ni)
                b[ni] = *(const bhalf8*)&Bs[(wx*32 + ni*16 + n16) * 64 + kk*32 + q4*8];
            #pragma unroll
            for (int mi = 0; mi < 2; ++mi)
                #pragma unroll
                for (int ni = 0; ni < 2; ++ni)
                    acc[mi][ni] = __builtin_amdgcn_mfma_f32_16x16x32_bf16(
                        a[mi], b[ni], acc[mi][ni], 0, 0, 0);
        }
        __syncthreads();
    }

    #pragma unroll
    for (int mi = 0; mi < 2; ++mi) {
        #pragma unroll
        for (int rr = 0; rr < 4; ++rr) {
            const int row = bm + wy*32 + mi*16 + q4*4 + rr;
            #pragma unroll
            for (int ni = 0; ni < 2; ++ni) {
                const int col = bn + wx*32 + ni*16 + n16;
                out[(size_t)row * D_ + col] = acc[mi][ni][rr];
            }
        }
    }
}

// ---------------------------------------------------------------------------
extern "C" void kernel_launch(void* const* d_in, const int* in_sizes, int n_in,
                              void* d_out, int out_size, void* d_ws, size_t ws_size,
                              hipStream_t stream)
{
    (void)out_size; (void)ws_size;
    const void* in_x = nullptr; const void* in_wqkv = nullptr;
    const void* in_wq = nullptr; const void* in_wk = nullptr;
    const void* in_core = nullptr; const void* in_wo = nullptr;
    for (int i = 0; i < n_in; ++i) {
        const int s = in_sizes[i];
        if      (s == BT_*D_)     { if (!in_x)    in_x    = d_in[i]; }
        else if (s == D_*3*D_)    { if (!in_wqkv) in_wqkv = d_in[i]; }
        else if (s == H_*DH_*R_)  { if (!in_wq)   in_wq   = d_in[i]; else if (!in_wk) in_wk = d_in[i]; }
        else if (s == H_*R_)      { if (!in_core) in_core = d_in[i]; }
        else if (s == D_*D_)      { if (!in_wo)   in_wo   = d_in[i]; }
    }
    if (!in_x)    in_x    = d_in[0];
    if (!in_wqkv) in_wqkv = d_in[1];
    if (!in_wq)   in_wq   = d_in[2];
    if (!in_wk)   in_wk   = d_in[3];
    if (!in_core) in_core = d_in[4];
    if (!in_wo)   in_wo   = d_in[5];

    float* out = (float*)d_out;

    char* ws    = (char*)d_ws;
    u16*  xb    = (u16*)(ws + WSB_XB);
    u16*  WcatT = (u16*)(ws + WSB_WCATT);
    u16*  ql    = (u16*)(ws + WSB_QL);
    u16*  kl    = (u16*)(ws + WSB_KL);
    u16*  vf    = (u16*)(ws + WSB_VT);
    u16*  yb    = (u16*)(ws + WSB_YB);
    u16*  WoT   = (u16*)(ws + WSB_WOT);

    prep_kernel<<<2688, 256, 0, stream>>>(in_x, xb, in_wqkv, in_wo,
                                          in_wq, in_wk, in_core, WcatT, WoT);
    gemm1_mfma<<<dim3(32, 32), 256, 0, stream>>>(xb, WcatT, ql, kl, vf);
    attn_kernel<<<1024, 256, 0, stream>>>(ql, kl, vf, yb);
    out_gemm_mfma<<<dim3(16, 64), 256, 0, stream>>>(yb, WoT, out);
}

// Round 7
// 176.695 us; speedup vs baseline: 1.0555x; 1.0555x over previous
//
#include <hip/hip_runtime.h>
#include <hip/hip_bf16.h>

// Rounds 0-17 established: fp32 inputs (inline detector), fp32 out, bf16
// MFMA everywhere. R10: loads issued just before a __syncthreads are
// DEFEATED (barrier drains vmcnt(0)). R12: swapped-QK attn, lane-local
// softmax, exp2-domain, rescale-skip. R13: zero-LDS P path (sigma order).
// R14: 512-thr attn, one staging serves 8 waves, complementary pairing.
// R15/R16: gload_lds GEMM staging + TLP + dispatch fusion. R17: barrier-
// free attn FALSIFIED the LDS/barrier theory (conflicts 0, dur 43->48.6):
// the cost was never barriers — per-wave global fragment reads amplified
// L2 traffic 8x (lost block-level sharing). Keeper: vfrag (V pre-laid in
// MFMA B-frag order by gemm1 -> V staging becomes a LINEAR copy).
// R18 (this round): R14 structure + vfrag +
//  - V staged via gload16 direct-to-LDS into double-buffered vsT; the
//    gload for tile it+1 is issued AFTER the post-staging barrier (during
//    compute of it), so barrier drains only ever wait on loads issued a
//    full compute-phase earlier (R10-safe).
//  - O^T PV: O[c2] = mfma(bv, pa, .) — output cols become q=n16, so
//    alpha/l/epilogue are LANE-LOCAL (no broadcast shuffles, 4x8B stores).
//  - vsT reads lane-linear (conflict-free); kls padded (2-way max).
// Pre-committed: flat +-3 vs 183 -> structural floor, roofline next.
#define B_  2
#define T_  2048
#define D_  1024
#define H_  16
#define DH_ 64
#define R_  32
#define BT_ (B_*T_)          // 4096
#define BH_ (B_*H_)          // 32

typedef unsigned short u16;
typedef unsigned int   u32;
typedef __attribute__((ext_vector_type(8))) short bhalf8;   // 8 bf16 = 4 VGPRs
typedef __attribute__((ext_vector_type(4))) float floatx4;  // MFMA C/D

// Workspace layout (bytes). Total ~38 MB.
#define WSB_FLAG  0
#define WSB_XB    256                        // bf16 x     (4096,1024)  8 MB
#define WSB_WCATT (WSB_XB    + 8388608)      // bf16 WcatT (2048,1024)  4 MB
#define WSB_QL    (WSB_WCATT + 4194304)      // bf16 (B,H,T,R)          4 MB
#define WSB_KL    (WSB_QL    + 4194304)      // bf16 (B,H,T,R)          4 MB
#define WSB_VT    (WSB_KL    + 4194304)      // bf16 vfrag (B,H,...)    8 MB
#define WSB_YB    (WSB_VT    + 8388608)      // bf16 y     (B,T,D)      8 MB
#define WSB_WOT   (WSB_YB    + 8388608)      // bf16 WoT   (1024,1024)  2 MB

#define NEG_ -1.0e30f

__device__ __forceinline__ float bfs(u16 s) {
    union { u32 i; float f; } w; w.i = ((u32)s) << 16; return w.f;
}
__device__ __forceinline__ u16 tob(float f) {
    __hip_bfloat16 h = __float2bfloat16(f);   // RNE
    return *(u16*)&h;
}
__device__ __forceinline__ u32 pack2(float a, float b) {
    return (u32)tob(a) | ((u32)tob(b) << 16);
}
// Direct global->LDS staging, 16B/lane. LDS base wave-uniform; HW writes
// base + lane*16. Global address is per-lane.
__device__ __forceinline__ void gload16(const u16* g, u16* l) {
    __builtin_amdgcn_global_load_lds(
        (const __attribute__((address_space(1))) void*)g,
        (__attribute__((address_space(3))) void*)l, 16, 0, 0);
}
// Inline dtype detect (1 = bf16, 0 = fp32) from first 2KB of x.
__device__ __forceinline__ int detect_isbf(const u32* __restrict__ xw, int lane) {
    int hits = 0;
    #pragma unroll
    for (int i = 0; i < 8; ++i) {
        const u32 w = xw[lane + i * 64];
        const u32 h = w & 0xFFFFu;
        const u32 e = (h >> 7) & 0xFFu;
        if (h == 0u || (e >= 100u && e <= 150u)) ++hits;
    }
    #pragma unroll
    for (int off = 32; off; off >>= 1) hits += __shfl_down(hits, off, 64);
    return __shfl(hits, 0, 64) >= 300;
}

// ---------------------------------------------------------------------------
// Kernel P (R17): fused preprocessing.
//  blocks 0..2047   : x -> xb bf16 (8 elems/thread)
//  blocks 2048..2303: transposing convert W_v slice of Wqkv -> WcatT[1024..]
//  blocks 2304..2559: transposing convert W_o -> WoT
//  blocks 2560..2687: fold via MFMA (scale incl 1/sqrt(32)*log2(e))
// ---------------------------------------------------------------------------
__global__ __launch_bounds__(256) void prep_kernel(
    const void* __restrict__ x, u16* __restrict__ xb,
    const void* __restrict__ Wqkv, const void* __restrict__ Wo,
    const void* __restrict__ Wq_lsr, const void* __restrict__ Wk_lsr,
    const void* __restrict__ core,
    u16* __restrict__ WcatT, u16* __restrict__ WoT)
{
    __shared__ __align__(16) u16 Bq[128 * 72];   // fold [n=d][k=dh]; also T-tile
    __shared__ __align__(16) u16 Bk[128 * 72];
    __shared__ __align__(16) u16 Aq[32 * 72];    // fold [m=r][k=dh]
    __shared__ __align__(16) u16 Ak[32 * 72];
    const int tid  = threadIdx.x;
    const int lane = tid & 63;
    const int isbf = detect_isbf((const u32*)x, lane);
    const int blk  = blockIdx.x;
    const int w    = tid >> 6;
    const int n16  = lane & 15;
    const int q4   = lane >> 4;

    if (blk < 2048) {
        const int e = blk * 256 + tid;           // over 524288 (x8 elems)
        if (isbf) {
            ((uint4*)xb)[e] = ((const uint4*)x)[e];
        } else {
            float4 a0 = ((const float4*)x)[2*e];
            float4 a1 = ((const float4*)x)[2*e + 1];
            uint4 o;
            o.x = pack2(a0.x, a0.y); o.y = pack2(a0.z, a0.w);
            o.z = pack2(a1.x, a1.y); o.w = pack2(a1.z, a1.w);
            ((uint4*)xb)[e] = o;
        }
        return;
    }

    if (blk < 2560) {
        // transposing convert, 64x64 tiles (uses Bq as scratch tile)
        int t = blk - 2048;
        const void* src; u16* dst; int srcStride, srcColOff, dstRowOff;
        if (t < 256) { src = Wqkv; dst = WcatT; srcStride = 3*D_; srcColOff = 2*D_; dstRowOff = 1024; }
        else { t -= 256; src = Wo; dst = WoT; srcStride = D_; srcColOff = 0; dstRowOff = 0; }
        const int j0 = (t & 15) * 64;
        const int i0 = (t >> 4) * 64;
        #pragma unroll
        for (int p = 0; p < 2; ++p) {
            const int e = tid + p * 256;
            const int r = e >> 3, ch = e & 7;
            if (isbf) {
                uint4 v = *(const uint4*)((const u16*)src + (size_t)(i0 + r) * srcStride + srcColOff + j0 + ch*8);
                *(uint4*)&Bq[r * 72 + ch*8] = v;
            } else {
                const float* s = (const float*)src + (size_t)(i0 + r) * srcStride + srcColOff + j0 + ch*8;
                float4 a0 = *(const float4*)s;
                float4 a1 = *(const float4*)(s + 4);
                uint4 o;
                o.x = pack2(a0.x, a0.y); o.y = pack2(a0.z, a0.w);
                o.z = pack2(a1.x, a1.y); o.w = pack2(a1.z, a1.w);
                *(uint4*)&Bq[r * 72 + ch*8] = o;
            }
        }
        __syncthreads();
        #pragma unroll
        for (int p = 0; p < 2; ++p) {
            const int e = tid + p * 256;
            const int c = e >> 3, ch = e & 7;
            u16 tmp[8];
            #pragma unroll
            for (int j = 0; j < 8; ++j) tmp[j] = Bq[(ch*8 + j) * 72 + c];
            *(uint4*)(dst + (size_t)(dstRowOff + j0 + c) * D_ + i0 + ch*8) = *(uint4*)tmp;
        }
        return;
    }

    // fold: per head h, Cq(32x1024) = Aq_h^T(32x64) @ Wq_h(64x1024)
    const int fb = blk - 2560;          // 0..127
    const int h  = fb & 15;
    const int d0 = (fb >> 4) * 128;

    #pragma unroll
    for (int p = 0; p < 8; ++p) {
        const int e  = tid + p * 256;
        const int r  = e & 31, dh = e >> 5;
        float aq, ak;
        if (isbf) {
            aq = bfs(((const u16*)Wq_lsr)[(h*DH_ + dh)*R_ + r]);
            ak = bfs(((const u16*)Wk_lsr)[(h*DH_ + dh)*R_ + r]);
        } else {
            aq = ((const float*)Wq_lsr)[(h*DH_ + dh)*R_ + r];
            ak = ((const float*)Wk_lsr)[(h*DH_ + dh)*R_ + r];
        }
        Aq[r * 72 + dh] = tob(aq);
        Ak[r * 72 + dh] = tob(ak);
    }
    #pragma unroll
    for (int p = 0; p < 8; ++p) {
        const int e  = tid + p * 256;      // 0..2047
        const int n  = e >> 4, ch = e & 15;
        if (isbf) {
            uint2 wq = *(const uint2*)((const u16*)Wqkv + (size_t)(d0+n)*(3*D_) + h*DH_ + ch*4);
            uint2 wk = *(const uint2*)((const u16*)Wqkv + (size_t)(d0+n)*(3*D_) + D_ + h*DH_ + ch*4);
            *(uint2*)&Bq[n * 72 + ch*4] = wq;
            *(uint2*)&Bk[n * 72 + ch*4] = wk;
        } else {
            float4 fq = *(const float4*)((const float*)Wqkv + (size_t)(d0+n)*(3*D_) + h*DH_ + ch*4);
            float4 fk = *(const float4*)((const float*)Wqkv + (size_t)(d0+n)*(3*D_) + D_ + h*DH_ + ch*4);
            uint2 oq, ok;
            oq.x = pack2(fq.x, fq.y); oq.y = pack2(fq.z, fq.w);
            ok.x = pack2(fk.x, fk.y); ok.y = pack2(fk.z, fk.w);
            *(uint2*)&Bq[n * 72 + ch*4] = oq;
            *(uint2*)&Bk[n * 72 + ch*4] = ok;
        }
    }
    __syncthreads();

    floatx4 accq[2][2], acck[2][2];
    #pragma unroll
    for (int mi = 0; mi < 2; ++mi)
        #pragma unroll
        for (int ni = 0; ni < 2; ++ni) { accq[mi][ni] = (floatx4)(0.f); acck[mi][ni] = (floatx4)(0.f); }

    #pragma unroll
    for (int kk = 0; kk < 2; ++kk) {
        bhalf8 aqf[2], akf[2], bqf[2], bkf[2];
        #pragma unroll
        for (int mi = 0; mi < 2; ++mi) {
            aqf[mi] = *(const bhalf8*)&Aq[(mi*16 + n16) * 72 + kk*32 + q4*8];
            akf[mi] = *(const bhalf8*)&Ak[(mi*16 + n16) * 72 + kk*32 + q4*8];
        }
        #pragma unroll
        for (int ni = 0; ni < 2; ++ni) {
            bqf[ni] = *(const bhalf8*)&Bq[(w*32 + ni*16 + n16) * 72 + kk*32 + q4*8];
            bkf[ni] = *(const bhalf8*)&Bk[(w*32 + ni*16 + n16) * 72 + kk*32 + q4*8];
        }
        #pragma unroll
        for (int mi = 0; mi < 2; ++mi)
            #pragma unroll
            for (int ni = 0; ni < 2; ++ni) {
                accq[mi][ni] = __builtin_amdgcn_mfma_f32_16x16x32_bf16(aqf[mi], bqf[ni], accq[mi][ni], 0, 0, 0);
                acck[mi][ni] = __builtin_amdgcn_mfma_f32_16x16x32_bf16(akf[mi], bkf[ni], acck[mi][ni], 0, 0, 0);
            }
    }

    const float scale = (float)(0.17677669529663687 * 1.4426950408889634);
    #pragma unroll
    for (int mi = 0; mi < 2; ++mi) {
        #pragma unroll
        for (int rr = 0; rr < 4; ++rr) {
            const int r = mi*16 + q4*4 + rr;
            const float cc = (isbf ? bfs(((const u16*)core)[h*R_ + r])
                                   : ((const float*)core)[h*R_ + r]) * scale;
            #pragma unroll
            for (int ni = 0; ni < 2; ++ni) {
                const int d = d0 + w*32 + ni*16 + n16;
                WcatT[(size_t)(h*R_ + r) * D_ + d]       = tob(accq[mi][ni][rr] * cc);
                WcatT[(size_t)(512 + h*R_ + r) * D_ + d] = tob(acck[mi][ni][rr]);
            }
        }
    }
}

// ---------------------------------------------------------------------------
// Kernel 1 (R17): MFMA gemm1  xb(4096,1024) @ WcatT^T -> ql/kl + vfrag.
// 128x64 tile, BK=64, gload16 staging, 1024 blocks = 4/CU.
// v-epilogue writes vfrag: V in attn's MFMA fragment order,
// vfrag[bh][tile][kc][c2][lane=(qv*16+dh&15)][j], sigma folded in:
// s = 32*kc + 16*j2 + 4*qv + j10 (j = j2*4 + j10).
// ---------------------------------------------------------------------------
__global__ __launch_bounds__(256, 4) void gemm1_mfma(
    const u16* __restrict__ xb, const u16* __restrict__ WcatT,
    u16* __restrict__ ql, u16* __restrict__ kl, u16* __restrict__ vf)
{
    __shared__ __align__(16) u16 As[128 * 64];   // 16384 B, linear
    __shared__ __align__(16) u16 Bs[64 * 64];    //  8192 B, linear
    const int tid  = threadIdx.x;
    const int lane = tid & 63;
    const int w    = tid >> 6;
    const int n16  = lane & 15;
    const int q4   = lane >> 4;
    const int wx   = w & 1;          // n-half (32 cols)
    const int wy   = w >> 1;         // m-half (64 rows)
    const int bm   = blockIdx.y * 128;
    const int bn   = blockIdx.x * 64;
    const int lrow = lane >> 3;          // 0..7: row within 8-row stripe
    const int lcol = (lane & 7) * 8;     // u16 col within 64-col row

    floatx4 acc[4][2];
    #pragma unroll
    for (int i = 0; i < 4; ++i)
        #pragma unroll
        for (int j = 0; j < 2; ++j) acc[i][j] = (floatx4)(0.f);

    for (int kt = 0; kt < D_; kt += 64) {
        #pragma unroll
        for (int i = 0; i < 4; ++i) {
            const int r0 = w*32 + i*8;
            gload16(xb + (size_t)(bm + r0 + lrow) * D_ + kt + lcol, &As[r0 * 64]);
        }
        #pragma unroll
        for (int i = 0; i < 2; ++i) {
            const int r0 = w*16 + i*8;
            gload16(WcatT + (size_t)(bn + r0 + lrow) * D_ + kt + lcol, &Bs[r0 * 64]);
        }
        __syncthreads();
        #pragma unroll
        for (int kk = 0; kk < 2; ++kk) {
            bhalf8 a[4], b[2];
            #pragma unroll
            for (int mi = 0; mi < 4; ++mi)
                a[mi] = *(const bhalf8*)&As[(wy*64 + mi*16 + n16) * 64 + kk*32 + q4*8];
            #pragma unroll
            for (int ni = 0; ni < 2; ++ni)
                b[ni] = *(const bhalf8*)&Bs[(wx*32 + ni*16 + n16) * 64 + kk*32 + q4*8];
            #pragma unroll
            for (int mi = 0; mi < 4; ++mi)
                #pragma unroll
                for (int ni = 0; ni < 2; ++ni)
                    acc[mi][ni] = __builtin_amdgcn_mfma_f32_16x16x32_bf16(
                        a[mi], b[ni], acc[mi][ni], 0, 0, 0);
        }
        __syncthreads();
    }

    if (bn < 1024) {
        #pragma unroll
        for (int mi = 0; mi < 4; ++mi) {
            #pragma unroll
            for (int rr = 0; rr < 4; ++rr) {
                const int row = bm + wy*64 + mi*16 + q4*4 + rr;
                const int b   = row >> 11;
                const int t   = row & (T_ - 1);
                #pragma unroll
                for (int ni = 0; ni < 2; ++ni) {
                    const int col = bn + wx*32 + ni*16 + n16;
                    const u16 val = tob(acc[mi][ni][rr]);
                    if (col < 512) {
                        const int h = col >> 5, r = col & 31;
                        ql[((size_t)(b*H_ + h)*T_ + t)*R_ + r] = val;
                    } else {
                        const int c = col - 512; const int h = c >> 5, r = c & 31;
                        kl[((size_t)(b*H_ + h)*T_ + t)*R_ + r] = val;
                    }
                }
            }
        }
    } else {
        // v -> vfrag (attn fragment order). Thread owns V[t..t+3][dh].
        #pragma unroll
        for (int mi = 0; mi < 4; ++mi) {
            const int row0 = bm + wy*64 + mi*16 + q4*4;   // multiple of 4
            const int b  = row0 >> 11;
            const int t  = row0 & (T_ - 1);
            const int tile = t >> 7;
            const int sl   = t & 127;                     // sl % 4 == 0
            const int kc   = sl >> 5;
            const int j2   = (sl >> 4) & 1;
            const int qv   = (sl >> 2) & 3;
            #pragma unroll
            for (int ni = 0; ni < 2; ++ni) {
                const int c  = bn - 1024 + wx*32 + ni*16 + n16;  // 0..1023
                const int h  = c >> 6, dh = c & 63;
                const int bh = b*H_ + h;
                const int c2 = dh >> 4;
                const int lv = qv*16 + (dh & 15);
                u16* dst = vf + ((((size_t)bh*16 + tile)*4 + kc)*4 + c2)*512
                              + lv*8 + j2*4;
                uint2 o;
                o.x = pack2(acc[mi][ni][0], acc[mi][ni][1]);
                o.y = pack2(acc[mi][ni][2], acc[mi][ni][3]);
                *(uint2*)dst = o;
            }
        }
    }
}

// ---------------------------------------------------------------------------
// softmax update, one q-row per lane. R18: alpha/l fully lane-local
// (O^T PV makes O columns = lane's own q) — no broadcast shuffles.
// ---------------------------------------------------------------------------
__device__ __forceinline__ void softmax_update(
    floatx4 (&Sc)[8], float &mrow, float &lrow, floatx4 (&O)[4])
{
    float cmax[8];
    #pragma unroll
    for (int c = 0; c < 8; ++c)
        cmax[c] = fmaxf(fmaxf(Sc[c][0], Sc[c][1]), fmaxf(Sc[c][2], Sc[c][3]));
    float rmax = fmaxf(fmaxf(fmaxf(cmax[0], cmax[1]), fmaxf(cmax[2], cmax[3])),
                       fmaxf(fmaxf(cmax[4], cmax[5]), fmaxf(cmax[6], cmax[7])));
    rmax = fmaxf(rmax, __shfl_xor(rmax, 16, 64));
    rmax = fmaxf(rmax, __shfl_xor(rmax, 32, 64));

    const float mn = fmaxf(mrow, rmax);
    const int norescale = __all(rmax <= mrow);     // exact: alpha == 1

    float csum[8];
    #pragma unroll
    for (int c = 0; c < 8; ++c) {
        #pragma unroll
        for (int r = 0; r < 4; ++r)
            Sc[c][r] = __builtin_amdgcn_exp2f(Sc[c][r] - mn);
        csum[c] = (Sc[c][0] + Sc[c][1]) + (Sc[c][2] + Sc[c][3]);
    }
    float rsum = ((csum[0] + csum[1]) + (csum[2] + csum[3]))
               + ((csum[4] + csum[5]) + (csum[6] + csum[7]));
    rsum += __shfl_xor(rsum, 16, 64);
    rsum += __shfl_xor(rsum, 32, 64);

    if (norescale) {
        lrow += rsum;                              // mn == mrow exactly
    } else {
        const float alpha = __builtin_amdgcn_exp2f(mrow - mn);
        mrow = mn;
        lrow = lrow * alpha + rsum;
        #pragma unroll
        for (int c2 = 0; c2 < 4; ++c2)
            #pragma unroll
            for (int r = 0; r < 4; ++r) O[c2][r] *= alpha;
    }
}

// ---------------------------------------------------------------------------
// Kernel 2 (R18): swapped-QK flash attention, 512-thr blocks, 128-row
// q-tiles, complementary pairing. V staged via gload16 into double-buffered
// LINEAR vsT (vfrag order, sigma pre-applied); gload for tile it+1 issued
// after the post-staging barrier -> latency hidden under compute (R10-safe).
// PV computes O^T = mfma(V-frag, P-frag): O cols = q = n16 -> alpha/l/
// epilogue lane-local. kls padded (2-way max); vsT reads lane-linear.
// ---------------------------------------------------------------------------
__global__ __launch_bounds__(512, 4) void attn_kernel(
    const u16* __restrict__ ql, const u16* __restrict__ kl,
    const u16* __restrict__ vf, u16* __restrict__ y)
{
    __shared__ __align__(16) u16 kls[128 * 40];      // 10240 B, padded
    __shared__ __align__(16) u16 vsT[2][8192];       // 32768 B, linear dbuf

    const int tid  = threadIdx.x;
    const int lane = tid & 63;
    const int w    = tid >> 6;               // 0..7
    const int n16  = lane & 15;
    const int q4   = lane >> 4;
    const int bh   = blockIdx.x;
    const int by   = blockIdx.y;             // 0..15
    const int qt2  = (by < 8) ? (15 - by) : (by - 8);  // complementary pairs
    const int t0   = qt2 * 128;
    const int nt   = qt2 + 1;                // # of 128-wide s-tiles

    // Q fragment = B-operand of swapped QK^T; loads directly in frag layout.
    const u16* qlb = ql + (size_t)bh * T_ * R_;
    const bhalf8 aq = *(const bhalf8*)(qlb + (size_t)(t0 + w*16 + n16) * R_ + q4*8);

    const u16* klb = kl + (size_t)bh * T_ * R_;
    const u16* vfb = vf + (size_t)bh * 131072;   // 16 tiles * 8192 u16
    const int rk = tid >> 2, ck = (tid & 3) * 8; // kls: 128 rows x 32 cols

    // prologue: K(0) into regs, V(0) gloads into buf 0
    uint4 kc0 = *(const uint4*)(klb + (size_t)rk * R_ + ck);
    uint4 kn0 = kc0;
    gload16(vfb + (size_t)(w*2    ) * 512 + lane*8, &vsT[0][(w*2    ) * 512]);
    gload16(vfb + (size_t)(w*2 + 1) * 512 + lane*8, &vsT[0][(w*2 + 1) * 512]);

    float mrow = NEG_, lrow = 0.f;           // one q-row per lane
    floatx4 O[4];
    #pragma unroll
    for (int c = 0; c < 4; ++c) O[c] = (floatx4)(0.f);

    for (int it = 0; it < nt; ++it) {
        const int cur = it & 1;
        __syncthreads();                     // waves done with prior LDS
        *(uint4*)&kls[rk * 40 + ck] = kc0;
        __syncthreads();                     // drains V(it) gloads (issued
                                             // one compute-phase ago) + kls
        if (it + 1 < nt) {
            // issue NEXT tile's V gloads + K reg prefetch NOW: their
            // latency hides under this tile's compute (R10-safe: the next
            // barrier that drains them is one full compute-phase away).
            const u16* vnb = vfb + (size_t)(it + 1) * 8192;
            gload16(vnb + (size_t)(w*2    ) * 512 + lane*8, &vsT[cur ^ 1][(w*2    ) * 512]);
            gload16(vnb + (size_t)(w*2 + 1) * 512 + lane*8, &vsT[cur ^ 1][(w*2 + 1) * 512]);
            kn0 = *(const uint4*)(klb + (size_t)((it+1)*128 + rk) * R_ + ck);
        }

        // S^T: A = K-frag (m=s), B = Q-frag (n=q). Lane: q=n16, s=16c+4q4+r.
        floatx4 Sc[8];
        #pragma unroll
        for (int c = 0; c < 8; ++c) {
            bhalf8 ak = *(const bhalf8*)&kls[(16*c + n16) * 40 + q4*8];
            Sc[c] = __builtin_amdgcn_mfma_f32_16x16x32_bf16(ak, aq, (floatx4)(0.f), 0, 0, 0);
        }

        if (it == nt - 1) {
            const int tq = w*16 + n16;                 // local q row (0..127)
            #pragma unroll
            for (int c = 0; c < 8; ++c) {
                const int sb = 16*c + 4*q4;            // local s base (s0==t0)
                #pragma unroll
                for (int r = 0; r < 4; ++r)
                    if (sb + r > tq) Sc[c][r] = NEG_;
            }
        }

        softmax_update(Sc, mrow, lrow, O);

        // PV (O^T): A = V-frag from vsT (lane-linear b128), B = P-frag
        // packed from lane's own Sc (sigma order, R13). O cols = q = n16.
        const u16* vt = &vsT[cur][lane * 8];
        #pragma unroll
        for (int kc = 0; kc < 4; ++kc) {
            union { u32 wd[4]; bhalf8 v; } pu;
            pu.wd[0] = pack2(Sc[2*kc    ][0], Sc[2*kc    ][1]);
            pu.wd[1] = pack2(Sc[2*kc    ][2], Sc[2*kc    ][3]);
            pu.wd[2] = pack2(Sc[2*kc + 1][0], Sc[2*kc + 1][1]);
            pu.wd[3] = pack2(Sc[2*kc + 1][2], Sc[2*kc + 1][3]);
            const bhalf8 pa = pu.v;
            #pragma unroll
            for (int c2 = 0; c2 < 4; ++c2) {
                bhalf8 bv = *(const bhalf8*)(vt + (size_t)(kc*4 + c2) * 512);
                O[c2] = __builtin_amdgcn_mfma_f32_16x16x32_bf16(bv, pa, O[c2], 0, 0, 0);
            }
        }

        kc0 = kn0;
    }

    // Epilogue: fully lane-local. Lane holds O^T[dh = 16c2+4q4+rr][q = n16].
    const int b = bh >> 4, h = bh & 15;
    const float rl = 1.0f / lrow;
    const int t = t0 + w*16 + n16;
    u16* yr = y + ((size_t)b * T_ + t) * D_ + h * DH_;
    #pragma unroll
    for (int c2 = 0; c2 < 4; ++c2) {
        uint2 o;
        o.x = pack2(O[c2][0] * rl, O[c2][1] * rl);
        o.y = pack2(O[c2][2] * rl, O[c2][3] * rl);
        *(uint2*)(yr + 16*c2 + 4*q4) = o;
    }
}

// ---------------------------------------------------------------------------
// Kernel 3 (R16): MFMA out-gemm  yb(4096,1024) @ WoT^T -> out fp32.
// 64x64 tile, gload16 staging. Grid (16,64) = 1024 blocks = 4/CU.
// ---------------------------------------------------------------------------
__global__ __launch_bounds__(256, 4) void out_gemm_mfma(
    const u16* __restrict__ yb, const u16* __restrict__ WoT,
    float* __restrict__ out)
{
    __shared__ __align__(16) u16 As[64 * 64];   // 8192 B, linear
    __shared__ __align__(16) u16 Bs[64 * 64];   // 8192 B, linear
    const int tid  = threadIdx.x;
    const int lane = tid & 63;
    const int w    = tid >> 6;
    const int n16  = lane & 15;
    const int q4   = lane >> 4;
    const int wx   = w & 1;          // n-half (32 cols)
    const int wy   = w >> 1;         // m-half (32 rows)
    const int bm   = blockIdx.y * 64;
    const int bn   = blockIdx.x * 64;
    const int lrow = lane >> 3;
    const int lcol = (lane & 7) * 8;

    floatx4 acc[2][2];
    #pragma unroll
    for (int i = 0; i < 2; ++i)
        #pragma unroll
        for (int j = 0; j < 2; ++j) acc[i][j] = (floatx4)(0.f);

    for (int kt = 0; kt < D_; kt += 64) {
        #pragma unroll
        for (int i = 0; i < 2; ++i) {
            const int r0 = w*16 + i*8;
            gload16(yb  + (size_t)(bm + r0 + lrow) * D_ + kt + lcol, &As[r0 * 64]);
            gload16(WoT + (size_t)(bn + r0 + lrow) * D_ + kt + lcol, &Bs[r0 * 64]);
        }
        __syncthreads();
        #pragma unroll
        for (int kk = 0; kk < 2; ++kk) {
            bhalf8 a[2], b[2];
            #pragma unroll
            for (int mi = 0; mi < 2; ++mi)
                a[mi] = *(const bhalf8*)&As[(wy*32 + mi*16 + n16) * 64 + kk*32 + q4*8];
            #pragma unroll
            for (int ni = 0; ni < 2; ++ni)
                b[ni] = *(const bhalf8*)&Bs[(wx*32 + ni*16 + n16) * 64 + kk*32 + q4*8];
            #pragma unroll
            for (int mi = 0; mi < 2; ++mi)
                #pragma unroll
                for (int ni = 0; ni < 2; ++ni)
                    acc[mi][ni] = __builtin_amdgcn_mfma_f32_16x16x32_bf16(
                        a[mi], b[ni], acc[mi][ni], 0, 0, 0);
        }
        __syncthreads();
    }

    #pragma unroll
    for (int mi = 0; mi < 2; ++mi) {
        #pragma unroll
        for (int rr = 0; rr < 4; ++rr) {
            const int row = bm + wy*32 + mi*16 + q4*4 + rr;
            #pragma unroll
            for (int ni = 0; ni < 2; ++ni) {
                const int col = bn + wx*32 + ni*16 + n16;
                out[(size_t)row * D_ + col] = acc[mi][ni][rr];
            }
        }
    }
}

// ---------------------------------------------------------------------------
extern "C" void kernel_launch(void* const* d_in, const int* in_sizes, int n_in,
                              void* d_out, int out_size, void* d_ws, size_t ws_size,
                              hipStream_t stream)
{
    (void)out_size; (void)ws_size;
    const void* in_x = nullptr; const void* in_wqkv = nullptr;
    const void* in_wq = nullptr; const void* in_wk = nullptr;
    const void* in_core = nullptr; const void* in_wo = nullptr;
    for (int i = 0; i < n_in; ++i) {
        const int s = in_sizes[i];
        if      (s == BT_*D_)     { if (!in_x)    in_x    = d_in[i]; }
        else if (s == D_*3*D_)    { if (!in_wqkv) in_wqkv = d_in[i]; }
        else if (s == H_*DH_*R_)  { if (!in_wq)   in_wq   = d_in[i]; else if (!in_wk) in_wk = d_in[i]; }
        else if (s == H_*R_)      { if (!in_core) in_core = d_in[i]; }
        else if (s == D_*D_)      { if (!in_wo)   in_wo   = d_in[i]; }
    }
    if (!in_x)    in_x    = d_in[0];
    if (!in_wqkv) in_wqkv = d_in[1];
    if (!in_wq)   in_wq   = d_in[2];
    if (!in_wk)   in_wk   = d_in[3];
    if (!in_core) in_core = d_in[4];
    if (!in_wo)   in_wo   = d_in[5];

    float* out = (float*)d_out;

    char* ws    = (char*)d_ws;
    u16*  xb    = (u16*)(ws + WSB_XB);
    u16*  WcatT = (u16*)(ws + WSB_WCATT);
    u16*  ql    = (u16*)(ws + WSB_QL);
    u16*  kl    = (u16*)(ws + WSB_KL);
    u16*  vf    = (u16*)(ws + WSB_VT);
    u16*  yb    = (u16*)(ws + WSB_YB);
    u16*  WoT   = (u16*)(ws + WSB_WOT);

    prep_kernel<<<2688, 256, 0, stream>>>(in_x, xb, in_wqkv, in_wo,
                                          in_wq, in_wk, in_core, WcatT, WoT);
    gemm1_mfma<<<dim3(32, 32), 256, 0, stream>>>(xb, WcatT, ql, kl, vf);
    attn_kernel<<<dim3(32, 16), 512, 0, stream>>>(ql, kl, vf, yb);
    out_gemm_mfma<<<dim3(16, 64), 256, 0, stream>>>(yb, WoT, out);
}